// Round 3
// baseline (1049.919 us; speedup 1.0000x reference)
//
#include <hip/hip_runtime.h>

#define NB 64
#define EDGES 1048576   /* 64*1024*16 */
#define NTOT  65536
#define CAP1  524288    /* stage-2 edge buffer capacity (expected ~262K) */
#define CAP2  262144    /* stage-3 edge buffer capacity (expected ~65K) */

struct __align__(8) CsrE { int s; float w; };
struct Edge3 { int s; int d; float w; };

__global__ void k_zero32(int* __restrict__ p, int n){
  int i=blockIdx.x*256+threadIdx.x; if(i<n) p[i]=0;
}
__global__ void k_zerof(float* __restrict__ p, int n){
  int i=blockIdx.x*256+threadIdx.x; if(i<n) p[i]=0.f;
}

// Y[Ns x 128] = X[Ns x 128] @ W[128 x 128]; W staged in LDS (64 KB); fp32 acc.
__global__ __launch_bounds__(256) void matmul128(const float* __restrict__ X,
                                                 const float* __restrict__ W,
                                                 float* __restrict__ Y) {
  __shared__ float Wl[128*128];
  for (int t=threadIdx.x*4; t<128*128; t+=1024)
    *(float4*)&Wl[t] = *(const float4*)&W[t];
  __syncthreads();
  const int tr=threadIdx.x>>4, tc=threadIdx.x&15;
  const int row0 = blockIdx.x*64 + tr*4;
  const int col0 = tc*8;
  float acc[4][8];
  #pragma unroll
  for(int r=0;r<4;++r){
    #pragma unroll
    for(int c=0;c<8;++c) acc[r][c]=0.f;
  }
  for (int k=0;k<128;k+=4) {
    float4 a[4];
    #pragma unroll
    for(int r=0;r<4;++r) a[r]=*(const float4*)&X[(row0+r)*128+k];
    #pragma unroll
    for(int kk=0;kk<4;++kk) {
      const float4 b0=*(const float4*)&Wl[(k+kk)*128+col0];
      const float4 b1=*(const float4*)&Wl[(k+kk)*128+col0+4];
      #pragma unroll
      for(int r=0;r<4;++r) {
        const float av = kk==0?a[r].x : kk==1?a[r].y : kk==2?a[r].z : a[r].w;
        acc[r][0]+=av*b0.x; acc[r][1]+=av*b0.y; acc[r][2]+=av*b0.z; acc[r][3]+=av*b0.w;
        acc[r][4]+=av*b1.x; acc[r][5]+=av*b1.y; acc[r][6]+=av*b1.z; acc[r][7]+=av*b1.w;
      }
    }
  }
  #pragma unroll
  for(int r=0;r<4;++r){
    float4 o0; o0.x=acc[r][0]; o0.y=acc[r][1]; o0.z=acc[r][2]; o0.w=acc[r][3];
    float4 o1; o1.x=acc[r][4]; o1.y=acc[r][5]; o1.z=acc[r][6]; o1.w=acc[r][7];
    *(float4*)&Y[(row0+r)*128+col0]=o0;
    *(float4*)&Y[(row0+r)*128+col0+4]=o1;
  }
}

// deg[dst] += w ; cnt[dst] += 1
template<bool FI>
__global__ void k_deg_count(const int* __restrict__ edst, const float* __restrict__ ew,
                            const Edge3* __restrict__ eb, const int* __restrict__ pcnt, int cap,
                            float* __restrict__ deg, int* __restrict__ cnt) {
  int e = blockIdx.x*256 + threadIdx.x;
  int n = FI ? EDGES : (*pcnt < cap ? *pcnt : cap);
  if (e>=n) return;
  int d; float w;
  if (FI){ d=edst[e]; w=ew[e]; } else { d=eb[e].d; w=eb[e].w; }
  atomicAdd(&deg[d], w);
  atomicAdd(&cnt[d], 1);
}

__global__ void k_dinv(const float* __restrict__ deg, float* __restrict__ dinv, int ns){
  int v=blockIdx.x*256+threadIdx.x; if(v>=ns) return;
  dinv[v] = 1.0f/sqrtf(deg[v]+1.0f);
}

// exclusive scan of cnt[0..ns) -> rowptr, rowptr[ns]=total. single block of 1024.
__global__ __launch_bounds__(1024) void k_scan(const int* __restrict__ cnt, int* __restrict__ rowptr, int ns){
  __shared__ int tmp[1024];
  int carry=0;
  for (int base=0;base<ns;base+=1024){
    int i=base+threadIdx.x;
    int v=(i<ns)?cnt[i]:0;
    tmp[threadIdx.x]=v; __syncthreads();
    for(int off=1;off<1024;off<<=1){
      int t=(threadIdx.x>=off)?tmp[threadIdx.x-off]:0;
      __syncthreads();
      tmp[threadIdx.x]+=t;
      __syncthreads();
    }
    if(i<ns) rowptr[i]=carry+tmp[threadIdx.x]-v;
    carry += tmp[1023];
    __syncthreads();
  }
  if(threadIdx.x==0) rowptr[ns]=carry;
}

template<bool FI>
__global__ void k_scatter(const int* __restrict__ esrc, const int* __restrict__ edst,
                          const float* __restrict__ ew, const Edge3* __restrict__ eb,
                          const int* __restrict__ pcnt, int cap, const int* __restrict__ rowptr,
                          int* __restrict__ fill, CsrE* __restrict__ csr){
  int e=blockIdx.x*256+threadIdx.x;
  int n = FI?EDGES:(*pcnt < cap ? *pcnt : cap); if(e>=n) return;
  int s,d; float w;
  if(FI){ s=esrc[e]; d=edst[e]; w=ew[e]; } else { s=eb[e].s; d=eb[e].d; w=eb[e].w; }
  int pos=atomicAdd(&fill[d],1);
  CsrE c; c.s=s; c.w=w;
  csr[rowptr[d]+pos]=c;
}

// one wave per dst node: h = sum_e dinv[s]*w*dinv[v]*xw[s] + dinv[v]^2*xw[v] + bias
__global__ __launch_bounds__(256) void k_gather(const float* __restrict__ xw, const CsrE* __restrict__ csr,
        const int* __restrict__ rowptr, const float* __restrict__ dinv, const float* __restrict__ bias,
        float* __restrict__ h, int ns){
  int wv=threadIdx.x>>6, ln=threadIdx.x&63;
  int v=blockIdx.x*4+wv; if(v>=ns) return;
  float dv=dinv[v];
  int rs=rowptr[v], re=rowptr[v+1];
  float a0=0.f,a1=0.f;
  for(int e=rs;e<re;++e){
    CsrE en=csr[e];
    float coef=dinv[en.s]*en.w*dv;
    const float2 xs=*(const float2*)&xw[en.s*128+ln*2];
    a0+=coef*xs.x; a1+=coef*xs.y;
  }
  const float2 xv=*(const float2*)&xw[v*128+ln*2];
  float d2=dv*dv;
  h[v*128+ln*2]   = a0 + d2*xv.x + bias[ln*2];
  h[v*128+ln*2+1] = a1 + d2*xv.y + bias[ln*2+1];
}

// score[v] = sigmoid( (h[v] . p) / ||p|| )
__global__ __launch_bounds__(256) void k_score(const float* __restrict__ h, const float* __restrict__ p,
                                               float* __restrict__ score, int ns){
  int wv=threadIdx.x>>6, ln=threadIdx.x&63;
  int v=blockIdx.x*4+wv; if(v>=ns) return;
  const float2 hv=*(const float2*)&h[v*128+ln*2];
  float p0=p[ln*2], p1=p[ln*2+1];
  float z=hv.x*p0+hv.y*p1;
  float pp=p0*p0+p1*p1;
  #pragma unroll
  for(int m=32;m>0;m>>=1){ z+=__shfl_xor(z,m,64); pp+=__shfl_xor(pp,m,64); }
  if(ln==0) score[v]=1.0f/(1.0f+expf(-z/sqrtf(pp)));
}

// per-graph top-K by rank counting; selected SET matches jax.lax.top_k (ties -> smaller index).
template<int N, int K>
__global__ __launch_bounds__(1024) void k_topk(const float* __restrict__ score,
                                               int* __restrict__ inv, int* __restrict__ selold){
  __shared__ float s[N];
  __shared__ int pre[N];
  int g=blockIdx.x, i=threadIdx.x;
  int gv=g*N+i;
  float si=score[gv];
  s[i]=si; __syncthreads();
  int rank=0;
  for(int j=0;j<N;++j){
    float sj=s[j];
    rank += (sj>si) || (sj==si && j<i);
  }
  int sel = (rank<K)?1:0;
  pre[i]=sel; __syncthreads();
  for(int off=1;off<N;off<<=1){
    int t=(i>=off)?pre[i-off]:0;
    __syncthreads();
    pre[i]+=t;
    __syncthreads();
  }
  int ng = g*K+pre[i]-1;
  if(sel && ng < NB*K){ inv[gv]=ng; selold[ng]=gv; }
  else inv[gv]=-1;
}

// pooled X[new] = relu(h[old]*score[old]); old bounds-guarded (poison-proof)
__global__ __launch_bounds__(128) void k_pool(const float* __restrict__ h, const float* __restrict__ score,
                                              const int* __restrict__ selold, float* __restrict__ xo, int nsOld){
  int nn=blockIdx.x, f=threadIdx.x;
  int old=selold[nn];
  if((unsigned)old >= (unsigned)nsOld){ xo[nn*128+f]=0.f; return; }
  float sc=score[old];
  xo[nn*128+f]=fmaxf(h[old*128+f]*sc, 0.f);
}

// compact surviving edges with remapped endpoints (cap-guarded)
template<bool FI>
__global__ void k_remap(const int* __restrict__ esrc, const int* __restrict__ edst,
                        const float* __restrict__ ew, const Edge3* __restrict__ eb,
                        const int* __restrict__ pcnt, int cap, const int* __restrict__ inv,
                        Edge3* __restrict__ out, int ocap, int* __restrict__ octr){
  int e=blockIdx.x*256+threadIdx.x;
  int n=FI?EDGES:(*pcnt < cap ? *pcnt : cap); if(e>=n) return;
  int s,d; float w;
  if(FI){s=esrc[e];d=edst[e];w=ew[e];} else {s=eb[e].s;d=eb[e].d;w=eb[e].w;}
  int sl=inv[s], dl=inv[d];
  if(sl>=0 && dl>=0){
    int pos=atomicAdd(octr,1);
    if(pos<ocap){
      Edge3 o; o.s=sl; o.d=dl; o.w=w;
      out[pos]=o;
    }
  }
}

// per-graph: cat = [max || mean] over 128 nodes; out = sigmoid(cat.Wo + bo)
__global__ __launch_bounds__(128) void k_readout(const float* __restrict__ X, const float* __restrict__ Wo,
                                                 const float* __restrict__ bo, float* __restrict__ out){
  __shared__ float red[128];
  int g=blockIdx.x, f=threadIdx.x;
  float mx=-3.4e38f, sm=0.f;
  for(int nd=0;nd<128;++nd){
    float v=X[(g*128+nd)*128+f];
    mx=fmaxf(mx,v); sm+=v;
  }
  float mean=sm*(1.0f/128.0f);
  out[64+g*256+f]      =mx;
  out[64+g*256+128+f]  =mean;
  red[f]=mx*Wo[f]+mean*Wo[128+f];
  __syncthreads();
  for(int off=64;off>0;off>>=1){ if(f<off) red[f]+=red[f+off]; __syncthreads(); }
  if(f==0){ float z=red[0]+bo[0]; out[g]=1.0f/(1.0f+expf(-z)); }
}

extern "C" void kernel_launch(void* const* d_in, const int* in_sizes, int n_in,
                              void* d_out, int out_size, void* d_ws, size_t ws_size,
                              hipStream_t stream) {
  (void)in_sizes; (void)n_in;
  const float* x  = (const float*)d_in[0];
  const int*   ei = (const int*)d_in[1];
  const float* ew = (const float*)d_in[2];
  // d_in[3] = batch_index (unused; graphs are equal-sized)
  const float* W1=(const float*)d_in[4];  const float* b1=(const float*)d_in[5];  const float* p1=(const float*)d_in[6];
  const float* W2=(const float*)d_in[7];  const float* b2=(const float*)d_in[8];  const float* p2=(const float*)d_in[9];
  const float* W3=(const float*)d_in[10]; const float* b3=(const float*)d_in[11]; const float* p3=(const float*)d_in[12];
  const float* Wo=(const float*)d_in[13]; const float* bo=(const float*)d_in[14];
  float* out=(float*)d_out;

  // ---- compact workspace layout (total 86,901,248 B ~= 82.9 MiB) ----
  char* ws=(char*)d_ws;
  size_t cur=0;
  float* slot0=(float*)(ws+cur); cur+=33554432;          // 32 MB ping
  float* slot1=(float*)(ws+cur); cur+=33554432;          // 32 MB pong
  CsrE*  csr  =(CsrE*)(ws+cur);  cur+=(size_t)EDGES*8;   // 8 MB
  Edge3* e1   =(Edge3*)(ws+cur); cur+=(size_t)CAP1*12;   // 6 MB
  Edge3* e2   =(Edge3*)(ws+cur); cur+=(size_t)CAP2*12;   // 3 MB
  float* deg  =(float*)(ws+cur); cur+=262144;            // } deg+cnt+fill: one
  int*   cnt  =(int*)  (ws+cur); cur+=262144;            // } contiguous zone,
  int*   fill =(int*)  (ws+cur); cur+=262144;            // } zeroed per stage
  float* dinv =(float*)(ws+cur); cur+=262144;
  int*   rowptr=(int*) (ws+cur); cur+=262400;
  float* score=(float*)(ws+cur); cur+=262144;
  int*   inv  =(int*)  (ws+cur); cur+=262144;
  int*   selold=(int*) (ws+cur); cur+=131072;
  int*   ctr  =(int*)  (ws+cur); cur+=256;
  int* c1=ctr; int* c2=ctr+1;

  if (ws_size < cur) {
    // workspace too small: fail cleanly (diagnosable) instead of faulting
    k_zerof<<<(out_size+255)/256,256,0,stream>>>(out,out_size);
    return;
  }

  // zero ctr once (c1/c2 must persist across stages)
  k_zero32<<<1,256,0,stream>>>(ctr,64);

  // ---------------- stage 1: n=1024, Ns=65536, K=512 ----------------
  k_zero32<<<768,256,0,stream>>>((int*)deg,196608);      // deg+cnt+fill
  matmul128<<<NTOT/64,256,0,stream>>>(x,W1,slot0);
  k_deg_count<true><<<EDGES/256,256,0,stream>>>(ei+EDGES,ew,nullptr,nullptr,0,deg,cnt);
  k_dinv<<<NTOT/256,256,0,stream>>>(deg,dinv,NTOT);
  k_scan<<<1,1024,0,stream>>>(cnt,rowptr,NTOT);
  k_scatter<true><<<EDGES/256,256,0,stream>>>(ei,ei+EDGES,ew,nullptr,nullptr,0,rowptr,fill,csr);
  k_gather<<<NTOT/4,256,0,stream>>>(slot0,csr,rowptr,dinv,b1,slot1,NTOT);
  k_score<<<NTOT/4,256,0,stream>>>(slot1,p1,score,NTOT);
  k_topk<1024,512><<<NB,1024,0,stream>>>(score,inv,selold);
  k_pool<<<32768,128,0,stream>>>(slot1,score,selold,slot0,NTOT);
  k_remap<true><<<EDGES/256,256,0,stream>>>(ei,ei+EDGES,ew,nullptr,nullptr,0,inv,e1,CAP1,c1);

  // ---------------- stage 2: n=512, Ns=32768, K=256 ----------------
  k_zero32<<<768,256,0,stream>>>((int*)deg,196608);
  matmul128<<<32768/64,256,0,stream>>>(slot0,W2,slot1);
  k_deg_count<false><<<CAP1/256,256,0,stream>>>(nullptr,nullptr,e1,c1,CAP1,deg,cnt);
  k_dinv<<<32768/256,256,0,stream>>>(deg,dinv,32768);
  k_scan<<<1,1024,0,stream>>>(cnt,rowptr,32768);
  k_scatter<false><<<CAP1/256,256,0,stream>>>(nullptr,nullptr,nullptr,e1,c1,CAP1,rowptr,fill,csr);
  k_gather<<<32768/4,256,0,stream>>>(slot1,csr,rowptr,dinv,b2,slot0,32768);
  k_score<<<32768/4,256,0,stream>>>(slot0,p2,score,32768);
  k_topk<512,256><<<NB,512,0,stream>>>(score,inv,selold);
  k_pool<<<16384,128,0,stream>>>(slot0,score,selold,slot1,32768);
  k_remap<false><<<CAP1/256,256,0,stream>>>(nullptr,nullptr,nullptr,e1,c1,CAP1,inv,e2,CAP2,c2);

  // ---------------- stage 3: n=256, Ns=16384, K=128 ----------------
  k_zero32<<<768,256,0,stream>>>((int*)deg,196608);
  matmul128<<<16384/64,256,0,stream>>>(slot1,W3,slot0);
  k_deg_count<false><<<CAP2/256,256,0,stream>>>(nullptr,nullptr,e2,c2,CAP2,deg,cnt);
  k_dinv<<<16384/256,256,0,stream>>>(deg,dinv,16384);
  k_scan<<<1,1024,0,stream>>>(cnt,rowptr,16384);
  k_scatter<false><<<CAP2/256,256,0,stream>>>(nullptr,nullptr,nullptr,e2,c2,CAP2,rowptr,fill,csr);
  k_gather<<<16384/4,256,0,stream>>>(slot0,csr,rowptr,dinv,b3,slot1,16384);
  k_score<<<16384/4,256,0,stream>>>(slot1,p3,score,16384);
  k_topk<256,128><<<NB,256,0,stream>>>(score,inv,selold);
  k_pool<<<8192,128,0,stream>>>(slot1,score,selold,slot0,16384);

  // ---------------- readout ----------------
  k_readout<<<NB,128,0,stream>>>(slot0,Wo,bo,out);
}

// Round 4
// 513.481 us; speedup vs baseline: 2.0447x; 2.0447x over previous
//
#include <hip/hip_runtime.h>

#define NB 64
#define EDGES 1048576   /* 64*1024*16 */
#define NTOT  65536

struct __align__(8) CsrE { int s; float w; };

__global__ void k_zero32(int* __restrict__ p, int n){
  int i=blockIdx.x*256+threadIdx.x; if(i<n) p[i]=0;
}
__global__ void k_zerof(float* __restrict__ p, int n){
  int i=blockIdx.x*256+threadIdx.x; if(i<n) p[i]=0.f;
}

// Y[ns x 128] = A[ns x 128] @ W[128 x 128]; W staged in LDS (64 KB); fp32 acc.
// G=true: A-row r is gathered+pooled on the fly: relu(h[selold[r]] * score[selold[r]])
template<bool G>
__global__ __launch_bounds__(256) void matmul128(const float* __restrict__ X,
                                                 const float* __restrict__ W,
                                                 const int* __restrict__ selold,
                                                 const float* __restrict__ score,
                                                 float* __restrict__ Y) {
  __shared__ float Wl[128*128];
  for (int t=threadIdx.x*4; t<128*128; t+=1024)
    *(float4*)&Wl[t] = *(const float4*)&W[t];
  __syncthreads();
  const int tr=threadIdx.x>>4, tc=threadIdx.x&15;
  const int row0 = blockIdx.x*64 + tr*4;
  const int col0 = tc*8;
  int oldr[4]; float scr[4];
  #pragma unroll
  for(int r=0;r<4;++r){
    if(G){ oldr[r]=selold[row0+r]; scr[r]=score[oldr[r]]; }
    else { oldr[r]=row0+r; scr[r]=1.f; }
  }
  float acc[4][8];
  #pragma unroll
  for(int r=0;r<4;++r){
    #pragma unroll
    for(int c=0;c<8;++c) acc[r][c]=0.f;
  }
  for (int k=0;k<128;k+=4) {
    float4 a[4];
    #pragma unroll
    for(int r=0;r<4;++r){
      a[r]=*(const float4*)&X[(size_t)oldr[r]*128+k];
      if(G){
        a[r].x=fmaxf(a[r].x*scr[r],0.f); a[r].y=fmaxf(a[r].y*scr[r],0.f);
        a[r].z=fmaxf(a[r].z*scr[r],0.f); a[r].w=fmaxf(a[r].w*scr[r],0.f);
      }
    }
    #pragma unroll
    for(int kk=0;kk<4;++kk) {
      const float4 b0=*(const float4*)&Wl[(k+kk)*128+col0];
      const float4 b1=*(const float4*)&Wl[(k+kk)*128+col0+4];
      #pragma unroll
      for(int r=0;r<4;++r) {
        const float av = kk==0?a[r].x : kk==1?a[r].y : kk==2?a[r].z : a[r].w;
        acc[r][0]+=av*b0.x; acc[r][1]+=av*b0.y; acc[r][2]+=av*b0.z; acc[r][3]+=av*b0.w;
        acc[r][4]+=av*b1.x; acc[r][5]+=av*b1.y; acc[r][6]+=av*b1.z; acc[r][7]+=av*b1.w;
      }
    }
  }
  #pragma unroll
  for(int r=0;r<4;++r){
    float4 o0; o0.x=acc[r][0]; o0.y=acc[r][1]; o0.z=acc[r][2]; o0.w=acc[r][3];
    float4 o1; o1.x=acc[r][4]; o1.y=acc[r][5]; o1.z=acc[r][6]; o1.w=acc[r][7];
    *(float4*)&Y[(size_t)(row0+r)*128+col0]=o0;
    *(float4*)&Y[(size_t)(row0+r)*128+col0+4]=o1;
  }
}

// cnt[dst]++ over all original edges
__global__ void k_cnt(const int* __restrict__ edst, int* __restrict__ cnt){
  int e=blockIdx.x*256+threadIdx.x; if(e>=EDGES) return;
  atomicAdd(&cnt[edst[e]],1);
}

// hierarchical exclusive scan of cnt[0..65536) -> rowptr (rowptr[65536]=EDGES)
__global__ __launch_bounds__(1024) void scan_local(const int* __restrict__ cnt,
                                                   int* __restrict__ rowptr, int* __restrict__ bsum){
  __shared__ int tmp[1024];
  int b=blockIdx.x, i=threadIdx.x;
  int v=cnt[b*1024+i];
  tmp[i]=v; __syncthreads();
  for(int off=1;off<1024;off<<=1){
    int t=(i>=off)?tmp[i-off]:0; __syncthreads();
    tmp[i]+=t; __syncthreads();
  }
  rowptr[b*1024+i]=tmp[i]-v;
  if(i==1023) bsum[b]=tmp[1023];
}
__global__ __launch_bounds__(1024) void scan_add(int* __restrict__ rowptr, const int* __restrict__ bsum){
  __shared__ int base;
  int b=blockIdx.x, i=threadIdx.x;
  if(i==0){ int s=0; for(int j=0;j<b;++j) s+=bsum[j]; base=s; }
  __syncthreads();
  rowptr[b*1024+i]+=base;
  if(b==0 && i==0) rowptr[65536]=EDGES;
}

__global__ void k_scatter(const int* __restrict__ esrc, const int* __restrict__ edst,
                          const float* __restrict__ ew, const int* __restrict__ rowptr,
                          int* __restrict__ fill, CsrE* __restrict__ csr){
  int e=blockIdx.x*256+threadIdx.x; if(e>=EDGES) return;
  int d=edst[e];
  int pos=atomicAdd(&fill[d],1);
  CsrE c; c.s=esrc[e]; c.w=ew[e];
  csr[rowptr[d]+pos]=c;
}

// dinv[v] = rsqrt(1 + sum_{live e in row(d0)} w)   (atomics-free row walk)
// L=0: d0=v, no filter. L=1: d0=mapA[v], src live iff inv1[s]>=0.
// L=2: d0=mapB[mapA[v]], src live iff inv2[inv1[s]]>=0.
template<int L>
__global__ void k_degrow(const int* __restrict__ rowptr, const CsrE* __restrict__ csr,
                         const int* __restrict__ mapA, const int* __restrict__ mapB,
                         const int* __restrict__ inv1, const int* __restrict__ inv2,
                         float* __restrict__ dinv, int ns){
  int v=blockIdx.x*256+threadIdx.x; if(v>=ns) return;
  int d0 = (L==0)? v : ((L==1)? mapA[v] : mapB[mapA[v]]);
  int rs=rowptr[d0], re=rowptr[d0+1];
  float s=0.f;
  for(int e=rs;e<re;++e){
    CsrE en=csr[e];
    bool live=true;
    if(L>=1){ int t=inv1[en.s]; live=(t>=0); if(L==2&&live){ t=inv2[t]; live=(t>=0);} }
    if(live) s+=en.w;
  }
  dinv[v]=rsqrtf(s+1.0f);
}

// one wave per node: h = dv*sum_e dinv[s']*w*xw[s'] + dv^2*xw[v] + bias ; fused score
template<int L>
__global__ __launch_bounds__(256) void k_gather(const float* __restrict__ xw, const CsrE* __restrict__ csr,
        const int* __restrict__ rowptr, const int* __restrict__ mapA, const int* __restrict__ mapB,
        const int* __restrict__ inv1, const int* __restrict__ inv2,
        const float* __restrict__ dinv, const float* __restrict__ bias, const float* __restrict__ p,
        float* __restrict__ h, float* __restrict__ score, int ns){
  int wv=threadIdx.x>>6, ln=threadIdx.x&63;
  int v=blockIdx.x*4+wv; if(v>=ns) return;
  int d0 = (L==0)? v : ((L==1)? mapA[v] : mapB[mapA[v]]);
  float dv=dinv[v];
  int rs=rowptr[d0], re=rowptr[d0+1];
  float a0=0.f,a1=0.f;
  for(int base=rs; base<re; base+=64){
    int len=re-base; if(len>64) len=64;
    int sidx=0; float cf=0.f;
    if(ln<len){
      CsrE en=csr[base+ln];
      int s=en.s; bool live=true;
      if(L>=1){ int t=inv1[s]; live=(t>=0); s=live?t:0; }
      if(L==2&&live){ int t=inv2[s]; live=(t>=0); s=live?t:0; }
      if(live){ sidx=s; cf=dinv[s]*en.w; }
    }
    for(int j=0;j<len;++j){
      float c=__shfl(cf,j,64);
      if(c==0.f) continue;               // wave-uniform skip of dead edges
      int si=__shfl(sidx,j,64);
      const float2 xs=*(const float2*)&xw[(size_t)si*128+ln*2];
      a0+=c*xs.x; a1+=c*xs.y;
    }
  }
  const float2 xv=*(const float2*)&xw[(size_t)v*128+ln*2];
  float d2=dv*dv;
  float h0 = a0*dv + d2*xv.x + bias[ln*2];
  float h1 = a1*dv + d2*xv.y + bias[ln*2+1];
  h[(size_t)v*128+ln*2]  =h0;
  h[(size_t)v*128+ln*2+1]=h1;
  float p0=p[ln*2], p1=p[ln*2+1];
  float z=h0*p0+h1*p1, pp=p0*p0+p1*p1;
  #pragma unroll
  for(int m=32;m>0;m>>=1){ z+=__shfl_xor(z,m,64); pp+=__shfl_xor(pp,m,64); }
  if(ln==0) score[v]=1.0f/(1.0f+expf(-z/sqrtf(pp)));
}

// per-graph top-K by rank counting; selected SET matches jax.lax.top_k (ties -> smaller index).
template<int N, int K>
__global__ __launch_bounds__(1024) void k_topk(const float* __restrict__ score,
                                               int* __restrict__ inv, int* __restrict__ selold){
  __shared__ float s[N];
  __shared__ int pre[N];
  int g=blockIdx.x, i=threadIdx.x;
  int gv=g*N+i;
  float si=score[gv];
  s[i]=si; __syncthreads();
  int rank=0;
  for(int j=0;j<N;++j){
    float sj=s[j];
    rank += (sj>si) || (sj==si && j<i);
  }
  int sel=(rank<K)?1:0;
  pre[i]=sel; __syncthreads();
  for(int off=1;off<N;off<<=1){
    int t=(i>=off)?pre[i-off]:0;
    __syncthreads();
    pre[i]+=t;
    __syncthreads();
  }
  int ng=g*K+pre[i]-1;
  if(sel && ng<NB*K){ inv[gv]=ng; selold[ng]=gv; }
  else inv[gv]=-1;
}

// per-graph readout with fused pool: v = relu(h3[selold3[.]] * score3[.])
__global__ __launch_bounds__(128) void k_readout(const float* __restrict__ h3, const float* __restrict__ score3,
                                                 const int* __restrict__ selold3,
                                                 const float* __restrict__ Wo, const float* __restrict__ bo,
                                                 float* __restrict__ out){
  __shared__ float red[128];
  int g=blockIdx.x, f=threadIdx.x;
  float mx=-3.4e38f, sm=0.f;
  for(int nd=0;nd<128;++nd){
    int old=selold3[g*128+nd];
    float v=fmaxf(h3[(size_t)old*128+f]*score3[old],0.f);
    mx=fmaxf(mx,v); sm+=v;
  }
  float mean=sm*(1.0f/128.0f);
  out[64+g*256+f]    =mx;
  out[64+g*256+128+f]=mean;
  red[f]=mx*Wo[f]+mean*Wo[128+f];
  __syncthreads();
  for(int off=64;off>0;off>>=1){ if(f<off) red[f]+=red[f+off]; __syncthreads(); }
  if(f==0){ float z=red[0]+bo[0]; out[g]=1.0f/(1.0f+expf(-z)); }
}

extern "C" void kernel_launch(void* const* d_in, const int* in_sizes, int n_in,
                              void* d_out, int out_size, void* d_ws, size_t ws_size,
                              hipStream_t stream) {
  (void)in_sizes; (void)n_in;
  const float* x  = (const float*)d_in[0];
  const int*   ei = (const int*)d_in[1];
  const float* ew = (const float*)d_in[2];
  // d_in[3] = batch_index (unused; graphs are equal-sized)
  const float* W1=(const float*)d_in[4];  const float* b1=(const float*)d_in[5];  const float* p1=(const float*)d_in[6];
  const float* W2=(const float*)d_in[7];  const float* b2=(const float*)d_in[8];  const float* p2=(const float*)d_in[9];
  const float* W3=(const float*)d_in[10]; const float* b3=(const float*)d_in[11]; const float* p3=(const float*)d_in[12];
  const float* Wo=(const float*)d_in[13]; const float* bo=(const float*)d_in[14];
  float* out=(float*)d_out;

  // ---- workspace layout (~73.9 MiB) ----
  char* ws=(char*)d_ws;
  size_t cur=0;
  float* slot0=(float*)(ws+cur); cur+=33554432;          // xw1 / xw2 / xw3
  float* slot1=(float*)(ws+cur); cur+=33554432;          // h1 / h2 / h3
  CsrE*  csr  =(CsrE*)(ws+cur);  cur+=(size_t)EDGES*8;   // 8 MB
  int*   rowptr=(int*) (ws+cur); cur+=262400;
  int*   cnt  =(int*)  (ws+cur); cur+=262144;            // } cnt+fill contiguous,
  int*   fill =(int*)  (ws+cur); cur+=262144;            // } zeroed together
  float* dinv1=(float*)(ws+cur); cur+=262144;
  float* dinv2=(float*)(ws+cur); cur+=131072;
  float* dinv3=(float*)(ws+cur); cur+=65536;
  float* sc1  =(float*)(ws+cur); cur+=262144;
  float* sc2  =(float*)(ws+cur); cur+=131072;
  float* sc3  =(float*)(ws+cur); cur+=65536;
  int*   inv1 =(int*)  (ws+cur); cur+=262144;
  int*   inv2 =(int*)  (ws+cur); cur+=131072;
  int*   invS =(int*)  (ws+cur); cur+=65536;
  int*   sel1 =(int*)  (ws+cur); cur+=131072;
  int*   sel2 =(int*)  (ws+cur); cur+=65536;
  int*   sel3 =(int*)  (ws+cur); cur+=32768;
  int*   bsum =(int*)  (ws+cur); cur+=256;

  if (ws_size < cur) {
    k_zerof<<<(out_size+255)/256,256,0,stream>>>(out,out_size);
    return;
  }

  const int* esrc=ei; const int* edst=ei+EDGES;

  // ---------------- stage 1: 65536 nodes, K=512/graph ----------------
  k_zero32<<<512,256,0,stream>>>(cnt,131072);                          // cnt+fill
  matmul128<false><<<NTOT/64,256,0,stream>>>(x,W1,nullptr,nullptr,slot0);
  k_cnt<<<EDGES/256,256,0,stream>>>(edst,cnt);
  scan_local<<<64,1024,0,stream>>>(cnt,rowptr,bsum);
  scan_add<<<64,1024,0,stream>>>(rowptr,bsum);
  k_scatter<<<EDGES/256,256,0,stream>>>(esrc,edst,ew,rowptr,fill,csr);
  k_degrow<0><<<NTOT/256,256,0,stream>>>(rowptr,csr,nullptr,nullptr,nullptr,nullptr,dinv1,NTOT);
  k_gather<0><<<NTOT/4,256,0,stream>>>(slot0,csr,rowptr,nullptr,nullptr,nullptr,nullptr,
                                       dinv1,b1,p1,slot1,sc1,NTOT);
  k_topk<1024,512><<<NB,1024,0,stream>>>(sc1,inv1,sel1);

  // ---------------- stage 2: 32768 nodes (space1), K=256 ----------------
  matmul128<true><<<32768/64,256,0,stream>>>(slot1,W2,sel1,sc1,slot0);
  k_degrow<1><<<32768/256,256,0,stream>>>(rowptr,csr,sel1,nullptr,inv1,nullptr,dinv2,32768);
  k_gather<1><<<32768/4,256,0,stream>>>(slot0,csr,rowptr,sel1,nullptr,inv1,nullptr,
                                        dinv2,b2,p2,slot1,sc2,32768);
  k_topk<512,256><<<NB,512,0,stream>>>(sc2,inv2,sel2);

  // ---------------- stage 3: 16384 nodes (space2), K=128 ----------------
  matmul128<true><<<16384/64,256,0,stream>>>(slot1,W3,sel2,sc2,slot0);
  k_degrow<2><<<16384/256,256,0,stream>>>(rowptr,csr,sel2,sel1,inv1,inv2,dinv3,16384);
  k_gather<2><<<16384/4,256,0,stream>>>(slot0,csr,rowptr,sel2,sel1,inv1,inv2,
                                        dinv3,b3,p3,slot1,sc3,16384);
  k_topk<256,128><<<NB,256,0,stream>>>(sc3,invS,sel3);

  // ---------------- readout (fused pool) ----------------
  k_readout<<<NB,128,0,stream>>>(slot1,sc3,sel3,Wo,bo,out);
}

// Round 5
// 461.641 us; speedup vs baseline: 2.2743x; 1.1123x over previous
//
#include <hip/hip_runtime.h>

#define NB 64
#define EDGES 1048576   /* 64*1024*16 */
#define NTOT  65536

struct __align__(8) CsrE { int s; float w; };

__global__ void k_zero32(int* __restrict__ p, int n){
  int i=blockIdx.x*256+threadIdx.x; if(i<n) p[i]=0;
}
__global__ void k_zerof(float* __restrict__ p, int n){
  int i=blockIdx.x*256+threadIdx.x; if(i<n) p[i]=0.f;
}

// Y[ns x 128] = A[ns x 128] @ W[128 x 128]; W staged in LDS (64 KB); fp32 acc.
// G=true: A-row r is gathered+pooled on the fly: relu(h[selold[r]] * score[selold[r]])
template<bool G>
__global__ __launch_bounds__(256) void matmul128(const float* __restrict__ X,
                                                 const float* __restrict__ W,
                                                 const int* __restrict__ selold,
                                                 const float* __restrict__ score,
                                                 float* __restrict__ Y) {
  __shared__ float Wl[128*128];
  for (int t=threadIdx.x*4; t<128*128; t+=1024)
    *(float4*)&Wl[t] = *(const float4*)&W[t];
  __syncthreads();
  const int tr=threadIdx.x>>4, tc=threadIdx.x&15;
  const int row0 = blockIdx.x*64 + tr*4;
  const int col0 = tc*8;
  int oldr[4]; float scr[4];
  #pragma unroll
  for(int r=0;r<4;++r){
    if(G){ oldr[r]=selold[row0+r]; scr[r]=score[oldr[r]]; }
    else { oldr[r]=row0+r; scr[r]=1.f; }
  }
  float acc[4][8];
  #pragma unroll
  for(int r=0;r<4;++r){
    #pragma unroll
    for(int c=0;c<8;++c) acc[r][c]=0.f;
  }
  for (int k=0;k<128;k+=4) {
    float4 a[4];
    #pragma unroll
    for(int r=0;r<4;++r){
      a[r]=*(const float4*)&X[(size_t)oldr[r]*128+k];
      if(G){
        a[r].x=fmaxf(a[r].x*scr[r],0.f); a[r].y=fmaxf(a[r].y*scr[r],0.f);
        a[r].z=fmaxf(a[r].z*scr[r],0.f); a[r].w=fmaxf(a[r].w*scr[r],0.f);
      }
    }
    #pragma unroll
    for(int kk=0;kk<4;++kk) {
      const float4 b0=*(const float4*)&Wl[(k+kk)*128+col0];
      const float4 b1=*(const float4*)&Wl[(k+kk)*128+col0+4];
      #pragma unroll
      for(int r=0;r<4;++r) {
        const float av = kk==0?a[r].x : kk==1?a[r].y : kk==2?a[r].z : a[r].w;
        acc[r][0]+=av*b0.x; acc[r][1]+=av*b0.y; acc[r][2]+=av*b0.z; acc[r][3]+=av*b0.w;
        acc[r][4]+=av*b1.x; acc[r][5]+=av*b1.y; acc[r][6]+=av*b1.z; acc[r][7]+=av*b1.w;
      }
    }
  }
  #pragma unroll
  for(int r=0;r<4;++r){
    float4 o0; o0.x=acc[r][0]; o0.y=acc[r][1]; o0.z=acc[r][2]; o0.w=acc[r][3];
    float4 o1; o1.x=acc[r][4]; o1.y=acc[r][5]; o1.z=acc[r][6]; o1.w=acc[r][7];
    *(float4*)&Y[(size_t)(row0+r)*128+col0]=o0;
    *(float4*)&Y[(size_t)(row0+r)*128+col0+4]=o1;
  }
}

// cnt[dst]++ over all original edges
__global__ void k_cnt(const int* __restrict__ edst, int* __restrict__ cnt){
  int e=blockIdx.x*256+threadIdx.x; if(e>=EDGES) return;
  atomicAdd(&cnt[edst[e]],1);
}

// hierarchical exclusive scan of cnt[0..65536) -> rowptr (rowptr[65536]=EDGES)
__global__ __launch_bounds__(1024) void scan_local(const int* __restrict__ cnt,
                                                   int* __restrict__ rowptr, int* __restrict__ bsum){
  __shared__ int tmp[1024];
  int b=blockIdx.x, i=threadIdx.x;
  int v=cnt[b*1024+i];
  tmp[i]=v; __syncthreads();
  for(int off=1;off<1024;off<<=1){
    int t=(i>=off)?tmp[i-off]:0; __syncthreads();
    tmp[i]+=t; __syncthreads();
  }
  rowptr[b*1024+i]=tmp[i]-v;
  if(i==1023) bsum[b]=tmp[1023];
}
__global__ __launch_bounds__(1024) void scan_add(int* __restrict__ rowptr, const int* __restrict__ bsum){
  __shared__ int base;
  int b=blockIdx.x, i=threadIdx.x;
  if(i==0){ int s=0; for(int j=0;j<b;++j) s+=bsum[j]; base=s; }
  __syncthreads();
  rowptr[b*1024+i]+=base;
  if(b==0 && i==0) rowptr[65536]=EDGES;
}

__global__ void k_scatter(const int* __restrict__ esrc, const int* __restrict__ edst,
                          const float* __restrict__ ew, const int* __restrict__ rowptr,
                          int* __restrict__ fill, CsrE* __restrict__ csr){
  int e=blockIdx.x*256+threadIdx.x; if(e>=EDGES) return;
  int d=edst[e];
  int pos=atomicAdd(&fill[d],1);
  CsrE c; c.s=esrc[e]; c.w=ew[e];
  csr[rowptr[d]+pos]=c;
}

// compose stage-3 maps: inv12[v0] = inv2[inv1[v0]] (or -1), map12[v] = sel1[sel2[v]]
__global__ void k_compose_inv(const int* __restrict__ inv1, const int* __restrict__ inv2,
                              int* __restrict__ inv12, int n){
  int v=blockIdx.x*256+threadIdx.x; if(v>=n) return;
  int t=inv1[v]; inv12[v]=(t>=0)?inv2[t]:-1;
}
__global__ void k_compose_map(const int* __restrict__ sel1, const int* __restrict__ sel2,
                              int* __restrict__ map12, int n){
  int v=blockIdx.x*256+threadIdx.x; if(v>=n) return;
  map12[v]=sel1[sel2[v]];
}

// dinv[v] = rsqrt(1 + sum_{live e in row(d0)} w); 4-wide unrolled row walk.
// F=false: d0=v, all edges live. F=true: d0=map[v], src live iff inv[s]>=0.
template<bool F>
__global__ void k_degrow(const int* __restrict__ rowptr, const CsrE* __restrict__ csr,
                         const int* __restrict__ map, const int* __restrict__ inv,
                         float* __restrict__ dinv, int ns){
  int v=blockIdx.x*256+threadIdx.x; if(v>=ns) return;
  int d0 = F? map[v] : v;
  int rs=rowptr[d0], re=rowptr[d0+1];
  float s0=0.f,s1=0.f,s2=0.f,s3=0.f;
  int e=rs;
  for(; e+4<=re; e+=4){
    CsrE e0=csr[e], e1=csr[e+1], e2=csr[e+2], e3=csr[e+3];
    if(!F || inv[e0.s]>=0) s0+=e0.w;
    if(!F || inv[e1.s]>=0) s1+=e1.w;
    if(!F || inv[e2.s]>=0) s2+=e2.w;
    if(!F || inv[e3.s]>=0) s3+=e3.w;
  }
  for(; e<re; ++e){
    CsrE en=csr[e];
    if(!F || inv[en.s]>=0) s0+=en.w;
  }
  dinv[v]=rsqrtf((s0+s1)+(s2+s3)+1.0f);
}

// one wave per node: h = dv*sum_e dinv[s']*w*xw[s'] + dv^2*xw[v] + bias ; fused score.
// Branch-free 4-edge-group inner loop: dead/pad edges carry coef 0 (load row 0, L1-hot).
template<bool F>
__global__ __launch_bounds__(256) void k_gather(const float* __restrict__ xw, const CsrE* __restrict__ csr,
        const int* __restrict__ rowptr, const int* __restrict__ map, const int* __restrict__ inv,
        const float* __restrict__ dinv, const float* __restrict__ bias, const float* __restrict__ p,
        float* __restrict__ h, float* __restrict__ score, int ns){
  int wv=threadIdx.x>>6, ln=threadIdx.x&63;
  int v=blockIdx.x*4+wv; if(v>=ns) return;
  int d0 = F? map[v] : v;
  float dv=dinv[v];
  int rs=rowptr[d0], re=rowptr[d0+1];
  float a0=0.f,a1=0.f,b0=0.f,b1=0.f;
  for(int base=rs; base<re; base+=64){
    int len=re-base; if(len>64) len=64;
    int sidx=0; float cf=0.f;
    if(ln<len){
      CsrE en=csr[base+ln];
      int s=en.s; bool live=true;
      if(F){ int t=inv[s]; live=(t>=0); s=live?t:0; }
      if(live){ sidx=s; cf=dinv[s]*en.w; }
    }
    int len4=(len+3)&~3;
    for(int j=0;j<len4;j+=4){
      float c0=__shfl(cf,j,64),   c1=__shfl(cf,j+1,64);
      float c2=__shfl(cf,j+2,64), c3=__shfl(cf,j+3,64);
      int   s0=__shfl(sidx,j,64),   s1=__shfl(sidx,j+1,64);
      int   s2=__shfl(sidx,j+2,64), s3=__shfl(sidx,j+3,64);
      const float2 x0=*(const float2*)&xw[(size_t)s0*128+ln*2];
      const float2 x1=*(const float2*)&xw[(size_t)s1*128+ln*2];
      const float2 x2=*(const float2*)&xw[(size_t)s2*128+ln*2];
      const float2 x3=*(const float2*)&xw[(size_t)s3*128+ln*2];
      a0+=c0*x0.x; a1+=c0*x0.y;
      b0+=c1*x1.x; b1+=c1*x1.y;
      a0+=c2*x2.x; a1+=c2*x2.y;
      b0+=c3*x3.x; b1+=c3*x3.y;
    }
  }
  a0+=b0; a1+=b1;
  const float2 xv=*(const float2*)&xw[(size_t)v*128+ln*2];
  float d2=dv*dv;
  float h0 = a0*dv + d2*xv.x + bias[ln*2];
  float h1 = a1*dv + d2*xv.y + bias[ln*2+1];
  h[(size_t)v*128+ln*2]  =h0;
  h[(size_t)v*128+ln*2+1]=h1;
  float p0=p[ln*2], p1=p[ln*2+1];
  float z=h0*p0+h1*p1, pp=p0*p0+p1*p1;
  #pragma unroll
  for(int m=32;m>0;m>>=1){ z+=__shfl_xor(z,m,64); pp+=__shfl_xor(pp,m,64); }
  if(ln==0) score[v]=1.0f/(1.0f+expf(-z/sqrtf(pp)));
}

// per-graph top-K by rank counting; selected SET matches jax.lax.top_k (ties -> smaller index).
template<int N, int K>
__global__ __launch_bounds__(1024) void k_topk(const float* __restrict__ score,
                                               int* __restrict__ inv, int* __restrict__ selold){
  __shared__ float s[N];
  __shared__ int pre[N];
  int g=blockIdx.x, i=threadIdx.x;
  int gv=g*N+i;
  float si=score[gv];
  s[i]=si; __syncthreads();
  int rank=0;
  for(int j=0;j<N;++j){
    float sj=s[j];
    rank += (sj>si) || (sj==si && j<i);
  }
  int sel=(rank<K)?1:0;
  pre[i]=sel; __syncthreads();
  for(int off=1;off<N;off<<=1){
    int t=(i>=off)?pre[i-off]:0;
    __syncthreads();
    pre[i]+=t;
    __syncthreads();
  }
  int ng=g*K+pre[i]-1;
  if(sel && ng<NB*K){ inv[gv]=ng; selold[ng]=gv; }
  else inv[gv]=-1;
}

// per-graph readout with fused pool: v = relu(h3[selold3[.]] * score3[.])
__global__ __launch_bounds__(128) void k_readout(const float* __restrict__ h3, const float* __restrict__ score3,
                                                 const int* __restrict__ selold3,
                                                 const float* __restrict__ Wo, const float* __restrict__ bo,
                                                 float* __restrict__ out){
  __shared__ float red[128];
  int g=blockIdx.x, f=threadIdx.x;
  float mx=-3.4e38f, sm=0.f;
  for(int nd=0;nd<128;++nd){
    int old=selold3[g*128+nd];
    float v=fmaxf(h3[(size_t)old*128+f]*score3[old],0.f);
    mx=fmaxf(mx,v); sm+=v;
  }
  float mean=sm*(1.0f/128.0f);
  out[64+g*256+f]    =mx;
  out[64+g*256+128+f]=mean;
  red[f]=mx*Wo[f]+mean*Wo[128+f];
  __syncthreads();
  for(int off=64;off>0;off>>=1){ if(f<off) red[f]+=red[f+off]; __syncthreads(); }
  if(f==0){ float z=red[0]+bo[0]; out[g]=1.0f/(1.0f+expf(-z)); }
}

extern "C" void kernel_launch(void* const* d_in, const int* in_sizes, int n_in,
                              void* d_out, int out_size, void* d_ws, size_t ws_size,
                              hipStream_t stream) {
  (void)in_sizes; (void)n_in;
  const float* x  = (const float*)d_in[0];
  const int*   ei = (const int*)d_in[1];
  const float* ew = (const float*)d_in[2];
  // d_in[3] = batch_index (unused; graphs are equal-sized)
  const float* W1=(const float*)d_in[4];  const float* b1=(const float*)d_in[5];  const float* p1=(const float*)d_in[6];
  const float* W2=(const float*)d_in[7];  const float* b2=(const float*)d_in[8];  const float* p2=(const float*)d_in[9];
  const float* W3=(const float*)d_in[10]; const float* b3=(const float*)d_in[11]; const float* p3=(const float*)d_in[12];
  const float* Wo=(const float*)d_in[13]; const float* bo=(const float*)d_in[14];
  float* out=(float*)d_out;

  // ---- workspace layout (~74.6 MiB) ----
  char* ws=(char*)d_ws;
  size_t cur=0;
  float* slot0=(float*)(ws+cur); cur+=33554432;          // xw1 / xw2 / xw3
  float* slot1=(float*)(ws+cur); cur+=33554432;          // h1 / h2 / h3
  CsrE*  csr  =(CsrE*)(ws+cur);  cur+=(size_t)EDGES*8;   // 8 MB
  int*   rowptr=(int*) (ws+cur); cur+=262400;
  int*   cnt  =(int*)  (ws+cur); cur+=262144;            // } cnt+fill contiguous,
  int*   fill =(int*)  (ws+cur); cur+=262144;            // } zeroed together
  float* dinv1=(float*)(ws+cur); cur+=262144;
  float* dinv2=(float*)(ws+cur); cur+=131072;
  float* dinv3=(float*)(ws+cur); cur+=65536;
  float* sc1  =(float*)(ws+cur); cur+=262144;
  float* sc2  =(float*)(ws+cur); cur+=131072;
  float* sc3  =(float*)(ws+cur); cur+=65536;
  int*   inv1 =(int*)  (ws+cur); cur+=262144;
  int*   inv2 =(int*)  (ws+cur); cur+=131072;
  int*   invS =(int*)  (ws+cur); cur+=65536;
  int*   inv12=(int*)  (ws+cur); cur+=262144;
  int*   sel1 =(int*)  (ws+cur); cur+=131072;
  int*   sel2 =(int*)  (ws+cur); cur+=65536;
  int*   sel3 =(int*)  (ws+cur); cur+=32768;
  int*   map12=(int*)  (ws+cur); cur+=65536;
  int*   bsum =(int*)  (ws+cur); cur+=256;

  if (ws_size < cur) {
    k_zerof<<<(out_size+255)/256,256,0,stream>>>(out,out_size);
    return;
  }

  const int* esrc=ei; const int* edst=ei+EDGES;

  // ---------------- stage 1: 65536 nodes, K=512/graph ----------------
  k_zero32<<<512,256,0,stream>>>(cnt,131072);                          // cnt+fill
  matmul128<false><<<NTOT/64,256,0,stream>>>(x,W1,nullptr,nullptr,slot0);
  k_cnt<<<EDGES/256,256,0,stream>>>(edst,cnt);
  scan_local<<<64,1024,0,stream>>>(cnt,rowptr,bsum);
  scan_add<<<64,1024,0,stream>>>(rowptr,bsum);
  k_scatter<<<EDGES/256,256,0,stream>>>(esrc,edst,ew,rowptr,fill,csr);
  k_degrow<false><<<NTOT/256,256,0,stream>>>(rowptr,csr,nullptr,nullptr,dinv1,NTOT);
  k_gather<false><<<NTOT/4,256,0,stream>>>(slot0,csr,rowptr,nullptr,nullptr,
                                           dinv1,b1,p1,slot1,sc1,NTOT);
  k_topk<1024,512><<<NB,1024,0,stream>>>(sc1,inv1,sel1);

  // ---------------- stage 2: 32768 nodes (space1), K=256 ----------------
  matmul128<true><<<32768/64,256,0,stream>>>(slot1,W2,sel1,sc1,slot0);
  k_degrow<true><<<32768/256,256,0,stream>>>(rowptr,csr,sel1,inv1,dinv2,32768);
  k_gather<true><<<32768/4,256,0,stream>>>(slot0,csr,rowptr,sel1,inv1,
                                           dinv2,b2,p2,slot1,sc2,32768);
  k_topk<512,256><<<NB,512,0,stream>>>(sc2,inv2,sel2);

  // ---------------- stage 3: 16384 nodes (space2), K=128 ----------------
  k_compose_inv<<<NTOT/256,256,0,stream>>>(inv1,inv2,inv12,NTOT);
  k_compose_map<<<16384/256,256,0,stream>>>(sel1,sel2,map12,16384);
  matmul128<true><<<16384/64,256,0,stream>>>(slot1,W3,sel2,sc2,slot0);
  k_degrow<true><<<16384/256,256,0,stream>>>(rowptr,csr,map12,inv12,dinv3,16384);
  k_gather<true><<<16384/4,256,0,stream>>>(slot0,csr,rowptr,map12,inv12,
                                           dinv3,b3,p3,slot1,sc3,16384);
  k_topk<256,128><<<NB,256,0,stream>>>(sc3,invS,sel3);

  // ---------------- readout (fused pool) ----------------
  k_readout<<<NB,128,0,stream>>>(slot1,sc3,sel3,Wo,bo,out);
}

// Round 6
// 421.916 us; speedup vs baseline: 2.4885x; 1.0942x over previous
//
#include <hip/hip_runtime.h>

#define NB 64
#define EDGES 1048576   /* 64*1024*16 */
#define NTOT  65536

struct __align__(8) CsrE { int s; float w; };

__global__ void k_zero32(int* __restrict__ p, int n){
  int i=blockIdx.x*256+threadIdx.x; if(i<n) p[i]=0;
}
__global__ void k_zerof(float* __restrict__ p, int n){
  int i=blockIdx.x*256+threadIdx.x; if(i<n) p[i]=0.f;
}

// Y[ns x 128] = A[ns x 128] @ W[128 x 128]; W staged in LDS (64 KB); fp32 acc.
// G=true: A-row r gathered+pooled on the fly: relu(h[selold[r]]*score[selold[r]]),
//         with XCD-aware block swizzle (8 graphs pinned per XCD for L2 locality).
template<bool G>
__global__ __launch_bounds__(256) void matmul128(const float* __restrict__ X,
                                                 const float* __restrict__ W,
                                                 const int* __restrict__ selold,
                                                 const float* __restrict__ score,
                                                 float* __restrict__ Y, int gshift) {
  __shared__ float Wl[128*128];
  for (int t=threadIdx.x*4; t<128*128; t+=1024)
    *(float4*)&Wl[t] = *(const float4*)&W[t];
  __syncthreads();
  const int tr=threadIdx.x>>4, tc=threadIdx.x&15;
  int row0;
  if(G){
    int b=blockIdx.x, xcd=b&7, slot=b>>3, bpg=1<<gshift;
    int graph=xcd*8+(slot>>gshift), idx=slot&(bpg-1);
    row0 = graph*(bpg<<6) + (idx<<6) + tr*4;
  } else row0 = blockIdx.x*64 + tr*4;
  const int col0 = tc*8;
  int oldr[4]; float scr[4];
  #pragma unroll
  for(int r=0;r<4;++r){
    if(G){ oldr[r]=selold[row0+r]; scr[r]=score[oldr[r]]; }
    else { oldr[r]=row0+r; scr[r]=1.f; }
  }
  float acc[4][8];
  #pragma unroll
  for(int r=0;r<4;++r){
    #pragma unroll
    for(int c=0;c<8;++c) acc[r][c]=0.f;
  }
  for (int k=0;k<128;k+=4) {
    float4 a[4];
    #pragma unroll
    for(int r=0;r<4;++r){
      a[r]=*(const float4*)&X[(size_t)oldr[r]*128+k];
      if(G){
        a[r].x=fmaxf(a[r].x*scr[r],0.f); a[r].y=fmaxf(a[r].y*scr[r],0.f);
        a[r].z=fmaxf(a[r].z*scr[r],0.f); a[r].w=fmaxf(a[r].w*scr[r],0.f);
      }
    }
    #pragma unroll
    for(int kk=0;kk<4;++kk) {
      const float4 b0=*(const float4*)&Wl[(k+kk)*128+col0];
      const float4 b1=*(const float4*)&Wl[(k+kk)*128+col0+4];
      #pragma unroll
      for(int r=0;r<4;++r) {
        const float av = kk==0?a[r].x : kk==1?a[r].y : kk==2?a[r].z : a[r].w;
        acc[r][0]+=av*b0.x; acc[r][1]+=av*b0.y; acc[r][2]+=av*b0.z; acc[r][3]+=av*b0.w;
        acc[r][4]+=av*b1.x; acc[r][5]+=av*b1.y; acc[r][6]+=av*b1.z; acc[r][7]+=av*b1.w;
      }
    }
  }
  #pragma unroll
  for(int r=0;r<4;++r){
    float4 o0; o0.x=acc[r][0]; o0.y=acc[r][1]; o0.z=acc[r][2]; o0.w=acc[r][3];
    float4 o1; o1.x=acc[r][4]; o1.y=acc[r][5]; o1.z=acc[r][6]; o1.w=acc[r][7];
    *(float4*)&Y[(size_t)(row0+r)*128+col0]=o0;
    *(float4*)&Y[(size_t)(row0+r)*128+col0+4]=o1;
  }
}

// cnt[dst]++ over all original edges
__global__ void k_cnt(const int* __restrict__ edst, int* __restrict__ cnt){
  int e=blockIdx.x*256+threadIdx.x; if(e>=EDGES) return;
  atomicAdd(&cnt[edst[e]],1);
}

// hierarchical exclusive scan of cnt[0..65536) -> rowptr (rowptr[65536]=EDGES)
__global__ __launch_bounds__(1024) void scan_local(const int* __restrict__ cnt,
                                                   int* __restrict__ rowptr, int* __restrict__ bsum){
  __shared__ int tmp[1024];
  int b=blockIdx.x, i=threadIdx.x;
  int v=cnt[b*1024+i];
  tmp[i]=v; __syncthreads();
  for(int off=1;off<1024;off<<=1){
    int t=(i>=off)?tmp[i-off]:0; __syncthreads();
    tmp[i]+=t; __syncthreads();
  }
  rowptr[b*1024+i]=tmp[i]-v;
  if(i==1023) bsum[b]=tmp[1023];
}
__global__ __launch_bounds__(1024) void scan_add(int* __restrict__ rowptr, const int* __restrict__ bsum){
  __shared__ int base;
  int b=blockIdx.x, i=threadIdx.x;
  if(i==0){ int s=0; for(int j=0;j<b;++j) s+=bsum[j]; base=s; }
  __syncthreads();
  rowptr[b*1024+i]+=base;
  if(b==0 && i==0) rowptr[65536]=EDGES;
}

__global__ void k_scatter(const int* __restrict__ esrc, const int* __restrict__ edst,
                          const float* __restrict__ ew, const int* __restrict__ rowptr,
                          int* __restrict__ fill, CsrE* __restrict__ csr){
  int e=blockIdx.x*256+threadIdx.x; if(e>=EDGES) return;
  int d=edst[e];
  int pos=atomicAdd(&fill[d],1);
  CsrE c; c.s=esrc[e]; c.w=ew[e];
  csr[rowptr[d]+pos]=c;
}

// compose stage-3 maps: inv12[v0] = inv2[inv1[v0]] (or -1), map12[v] = sel1[sel2[v]]
__global__ void k_compose_inv(const int* __restrict__ inv1, const int* __restrict__ inv2,
                              int* __restrict__ inv12, int n){
  int v=blockIdx.x*256+threadIdx.x; if(v>=n) return;
  int t=inv1[v]; inv12[v]=(t>=0)?inv2[t]:-1;
}
__global__ void k_compose_map(const int* __restrict__ sel1, const int* __restrict__ sel2,
                              int* __restrict__ map12, int n){
  int v=blockIdx.x*256+threadIdx.x; if(v>=n) return;
  map12[v]=sel1[sel2[v]];
}

// dinv[v] = rsqrt(1 + sum_{live e in row(d0)} w); 4-wide unrolled row walk.
template<bool F>
__global__ void k_degrow(const int* __restrict__ rowptr, const CsrE* __restrict__ csr,
                         const int* __restrict__ map, const int* __restrict__ inv,
                         float* __restrict__ dinv, int ns){
  int v=blockIdx.x*256+threadIdx.x; if(v>=ns) return;
  int d0 = F? map[v] : v;
  int rs=rowptr[d0], re=rowptr[d0+1];
  float s0=0.f,s1=0.f,s2=0.f,s3=0.f;
  int e=rs;
  for(; e+4<=re; e+=4){
    CsrE e0=csr[e], e1=csr[e+1], e2=csr[e+2], e3=csr[e+3];
    if(!F || inv[e0.s]>=0) s0+=e0.w;
    if(!F || inv[e1.s]>=0) s1+=e1.w;
    if(!F || inv[e2.s]>=0) s2+=e2.w;
    if(!F || inv[e3.s]>=0) s3+=e3.w;
  }
  for(; e<re; ++e){
    CsrE en=csr[e];
    if(!F || inv[en.s]>=0) s0+=en.w;
  }
  dinv[v]=rsqrtf((s0+s1)+(s2+s3)+1.0f);
}

// one wave per node, XCD-swizzled (8 graphs/XCD): h = dv*sum dinv[s']*w*xw[s'] + dv^2*xw[v] + bias;
// fused score. Branch-free 4-edge groups; dead/pad edges carry coef 0 (row-0 load, L1-hot).
template<bool F>
__global__ __launch_bounds__(256) void k_gather(const float* __restrict__ xw, const CsrE* __restrict__ csr,
        const int* __restrict__ rowptr, const int* __restrict__ map, const int* __restrict__ inv,
        const float* __restrict__ dinv, const float* __restrict__ bias, const float* __restrict__ p,
        float* __restrict__ h, float* __restrict__ score, int gshift, int ns){
  int wv=threadIdx.x>>6, ln=threadIdx.x&63;
  int b=blockIdx.x, xcd=b&7, slot=b>>3, bpg=1<<gshift;
  int graph=xcd*8+(slot>>gshift), idx=slot&(bpg-1);
  int v = graph*(bpg<<2) + (idx<<2) + wv;
  if(v>=ns) return;
  int d0 = F? map[v] : v;
  float dv=dinv[v];
  int rs=rowptr[d0], re=rowptr[d0+1];
  float a0=0.f,a1=0.f,b0=0.f,b1=0.f;
  for(int base=rs; base<re; base+=64){
    int len=re-base; if(len>64) len=64;
    int sidx=0; float cf=0.f;
    if(ln<len){
      CsrE en=csr[base+ln];
      int s=en.s; bool live=true;
      if(F){ int t=inv[s]; live=(t>=0); s=live?t:0; }
      if(live){ sidx=s; cf=dinv[s]*en.w; }
    }
    int len4=(len+3)&~3;
    for(int j=0;j<len4;j+=4){
      float c0=__shfl(cf,j,64),   c1=__shfl(cf,j+1,64);
      float c2=__shfl(cf,j+2,64), c3=__shfl(cf,j+3,64);
      int   s0=__shfl(sidx,j,64),   s1=__shfl(sidx,j+1,64);
      int   s2=__shfl(sidx,j+2,64), s3=__shfl(sidx,j+3,64);
      const float2 x0=*(const float2*)&xw[(size_t)s0*128+ln*2];
      const float2 x1=*(const float2*)&xw[(size_t)s1*128+ln*2];
      const float2 x2=*(const float2*)&xw[(size_t)s2*128+ln*2];
      const float2 x3=*(const float2*)&xw[(size_t)s3*128+ln*2];
      a0+=c0*x0.x; a1+=c0*x0.y;
      b0+=c1*x1.x; b1+=c1*x1.y;
      a0+=c2*x2.x; a1+=c2*x2.y;
      b0+=c3*x3.x; b1+=c3*x3.y;
    }
  }
  a0+=b0; a1+=b1;
  const float2 xv=*(const float2*)&xw[(size_t)v*128+ln*2];
  float d2=dv*dv;
  float h0 = a0*dv + d2*xv.x + bias[ln*2];
  float h1 = a1*dv + d2*xv.y + bias[ln*2+1];
  h[(size_t)v*128+ln*2]  =h0;
  h[(size_t)v*128+ln*2+1]=h1;
  float p0=p[ln*2], p1=p[ln*2+1];
  float z=h0*p0+h1*p1, pp=p0*p0+p1*p1;
  #pragma unroll
  for(int m=32;m>0;m>>=1){ z+=__shfl_xor(z,m,64); pp+=__shfl_xor(pp,m,64); }
  if(ln==0) score[v]=1.0f/(1.0f+expf(-z/sqrtf(pp)));
}

// per-graph top-K via 4-pass MSB radix select on fp32 bit pattern (positive floats
// are order-isomorphic to their u32 bits). Exact jax.lax.top_k set semantics:
// K largest, ties broken toward smaller index. O(N) DS traffic vs O(N^2) rank-count.
template<int N, int K>
__global__ __launch_bounds__(1024) void k_topk(const float* __restrict__ score,
                                               int* __restrict__ inv, int* __restrict__ selold){
  __shared__ unsigned hist[256];
  __shared__ unsigned sfx[256];
  __shared__ int c_sh, r_sh;
  __shared__ int pre[N];
  int g=blockIdx.x, i=threadIdx.x;
  int gv=g*N+i;
  unsigned key=__float_as_uint(score[gv]);
  int st=1;              // 0=rejected, 1=alive, 2=selected
  if(i==0) r_sh=K;
  __syncthreads();
  int R=K;
  #pragma unroll
  for(int pass=0; pass<4; ++pass){
    int shift=24-pass*8;
    if(i<256) hist[i]=0;
    __syncthreads();
    unsigned byte=(key>>shift)&255u;
    if(st==1) atomicAdd(&hist[byte],1u);
    __syncthreads();
    if(i<256) sfx[i]=hist[i];
    __syncthreads();
    for(int off=1; off<256; off<<=1){
      unsigned t=0;
      if(i<256 && i+off<256) t=sfx[i+off];
      __syncthreads();
      if(i<256) sfx[i]+=t;
      __syncthreads();
    }
    if(i<256){
      int A=(i<255)?(int)sfx[i+1]:0;
      if(A<R && R<=A+(int)hist[i]){ c_sh=i; r_sh=R-A; }
    }
    __syncthreads();
    int c=c_sh; R=r_sh;
    if(st==1){
      if((int)byte>c) st=2;
      else if((int)byte<c) st=0;
    }
    __syncthreads();
  }
  // alive keys all equal the threshold; pick R of them with smallest indices
  int alive=(st==1)?1:0;
  pre[i]=alive; __syncthreads();
  for(int off=1;off<N;off<<=1){
    int t=(i>=off)?pre[i-off]:0; __syncthreads();
    pre[i]+=t; __syncthreads();
  }
  int tie_rank=pre[i]-alive;          // exclusive rank among alive, by index
  int sel=(st==2)||(st==1 && tie_rank<R);
  __syncthreads();
  pre[i]=sel; __syncthreads();
  for(int off=1;off<N;off<<=1){
    int t=(i>=off)?pre[i-off]:0; __syncthreads();
    pre[i]+=t; __syncthreads();
  }
  int ng=g*K+pre[i]-1;
  if(sel && ng<NB*K){ inv[gv]=ng; selold[ng]=gv; }
  else inv[gv]=-1;
}

// per-graph readout with fused pool: v = relu(h3[selold3[.]] * score3[.])
__global__ __launch_bounds__(128) void k_readout(const float* __restrict__ h3, const float* __restrict__ score3,
                                                 const int* __restrict__ selold3,
                                                 const float* __restrict__ Wo, const float* __restrict__ bo,
                                                 float* __restrict__ out){
  __shared__ float red[128];
  int g=blockIdx.x, f=threadIdx.x;
  float mx=-3.4e38f, sm=0.f;
  for(int nd=0;nd<128;++nd){
    int old=selold3[g*128+nd];
    float v=fmaxf(h3[(size_t)old*128+f]*score3[old],0.f);
    mx=fmaxf(mx,v); sm+=v;
  }
  float mean=sm*(1.0f/128.0f);
  out[64+g*256+f]    =mx;
  out[64+g*256+128+f]=mean;
  red[f]=mx*Wo[f]+mean*Wo[128+f];
  __syncthreads();
  for(int off=64;off>0;off>>=1){ if(f<off) red[f]+=red[f+off]; __syncthreads(); }
  if(f==0){ float z=red[0]+bo[0]; out[g]=1.0f/(1.0f+expf(-z)); }
}

extern "C" void kernel_launch(void* const* d_in, const int* in_sizes, int n_in,
                              void* d_out, int out_size, void* d_ws, size_t ws_size,
                              hipStream_t stream) {
  (void)in_sizes; (void)n_in;
  const float* x  = (const float*)d_in[0];
  const int*   ei = (const int*)d_in[1];
  const float* ew = (const float*)d_in[2];
  // d_in[3] = batch_index (unused; graphs are equal-sized)
  const float* W1=(const float*)d_in[4];  const float* b1=(const float*)d_in[5];  const float* p1=(const float*)d_in[6];
  const float* W2=(const float*)d_in[7];  const float* b2=(const float*)d_in[8];  const float* p2=(const float*)d_in[9];
  const float* W3=(const float*)d_in[10]; const float* b3=(const float*)d_in[11]; const float* p3=(const float*)d_in[12];
  const float* Wo=(const float*)d_in[13]; const float* bo=(const float*)d_in[14];
  float* out=(float*)d_out;

  // ---- workspace layout (~74.6 MiB) ----
  char* ws=(char*)d_ws;
  size_t cur=0;
  float* slot0=(float*)(ws+cur); cur+=33554432;          // xw1 / xw2 / xw3
  float* slot1=(float*)(ws+cur); cur+=33554432;          // h1 / h2 / h3
  CsrE*  csr  =(CsrE*)(ws+cur);  cur+=(size_t)EDGES*8;   // 8 MB
  int*   rowptr=(int*) (ws+cur); cur+=262400;
  int*   cnt  =(int*)  (ws+cur); cur+=262144;            // } cnt+fill contiguous,
  int*   fill =(int*)  (ws+cur); cur+=262144;            // } zeroed together
  float* dinv1=(float*)(ws+cur); cur+=262144;
  float* dinv2=(float*)(ws+cur); cur+=131072;
  float* dinv3=(float*)(ws+cur); cur+=65536;
  float* sc1  =(float*)(ws+cur); cur+=262144;
  float* sc2  =(float*)(ws+cur); cur+=131072;
  float* sc3  =(float*)(ws+cur); cur+=65536;
  int*   inv1 =(int*)  (ws+cur); cur+=262144;
  int*   inv2 =(int*)  (ws+cur); cur+=131072;
  int*   invS =(int*)  (ws+cur); cur+=65536;
  int*   inv12=(int*)  (ws+cur); cur+=262144;
  int*   sel1 =(int*)  (ws+cur); cur+=131072;
  int*   sel2 =(int*)  (ws+cur); cur+=65536;
  int*   sel3 =(int*)  (ws+cur); cur+=32768;
  int*   map12=(int*)  (ws+cur); cur+=65536;
  int*   bsum =(int*)  (ws+cur); cur+=256;

  if (ws_size < cur) {
    k_zerof<<<(out_size+255)/256,256,0,stream>>>(out,out_size);
    return;
  }

  const int* esrc=ei; const int* edst=ei+EDGES;

  // ---------------- stage 1: 65536 nodes, K=512/graph ----------------
  k_zero32<<<512,256,0,stream>>>(cnt,131072);                          // cnt+fill
  matmul128<false><<<NTOT/64,256,0,stream>>>(x,W1,nullptr,nullptr,slot0,0);
  k_cnt<<<EDGES/256,256,0,stream>>>(edst,cnt);
  scan_local<<<64,1024,0,stream>>>(cnt,rowptr,bsum);
  scan_add<<<64,1024,0,stream>>>(rowptr,bsum);
  k_scatter<<<EDGES/256,256,0,stream>>>(esrc,edst,ew,rowptr,fill,csr);
  k_degrow<false><<<NTOT/256,256,0,stream>>>(rowptr,csr,nullptr,nullptr,dinv1,NTOT);
  k_gather<false><<<NTOT/4,256,0,stream>>>(slot0,csr,rowptr,nullptr,nullptr,
                                           dinv1,b1,p1,slot1,sc1,8,NTOT);
  k_topk<1024,512><<<NB,1024,0,stream>>>(sc1,inv1,sel1);

  // ---------------- stage 2: 32768 nodes (space1), K=256 ----------------
  matmul128<true><<<32768/64,256,0,stream>>>(slot1,W2,sel1,sc1,slot0,3);
  k_degrow<true><<<32768/256,256,0,stream>>>(rowptr,csr,sel1,inv1,dinv2,32768);
  k_gather<true><<<32768/4,256,0,stream>>>(slot0,csr,rowptr,sel1,inv1,
                                           dinv2,b2,p2,slot1,sc2,7,32768);
  k_topk<512,256><<<NB,512,0,stream>>>(sc2,inv2,sel2);

  // ---------------- stage 3: 16384 nodes (space2), K=128 ----------------
  k_compose_inv<<<NTOT/256,256,0,stream>>>(inv1,inv2,inv12,NTOT);
  k_compose_map<<<16384/256,256,0,stream>>>(sel1,sel2,map12,16384);
  matmul128<true><<<16384/64,256,0,stream>>>(slot1,W3,sel2,sc2,slot0,2);
  k_degrow<true><<<16384/256,256,0,stream>>>(rowptr,csr,map12,inv12,dinv3,16384);
  k_gather<true><<<16384/4,256,0,stream>>>(slot0,csr,rowptr,map12,inv12,
                                           dinv3,b3,p3,slot1,sc3,6,16384);
  k_topk<256,128><<<NB,256,0,stream>>>(sc3,invS,sel3);

  // ---------------- readout (fused pool) ----------------
  k_readout<<<NB,128,0,stream>>>(slot1,sc3,sel3,Wo,bo,out);
}